// Round 9
// baseline (643.889 us; speedup 1.0000x reference)
//
#include <hip/hip_runtime.h>
#include <hip/hip_bf16.h>
#include <hip/hip_cooperative_groups.h>

namespace cg = cooperative_groups;

#define D 128
#define NG 128
#define CSR_BLOCKS 512

typedef __attribute__((ext_vector_type(8))) short bf16x8;
typedef __attribute__((ext_vector_type(4))) float f32x4;

__device__ inline unsigned short f2bf(float f) {
  union { float f; unsigned u; } c; c.f = f;
  unsigned u = c.u;
  return (unsigned short)((u + 0x7FFFu + ((u >> 16) & 1u)) >> 16);  // RNE
}
__device__ inline float bf2f(unsigned short b) {
  union { unsigned u; float f; } c; c.u = ((unsigned)b) << 16;
  return c.f;
}

// Transpose + bf16-convert weights: Wt[l][n][k] = bf16(W[l][k][n]).
// Also zeroes deg[]/g[] and computes pool graph bounds (folded launches).
__global__ void prep_w(const float* __restrict__ W1, const float* __restrict__ W2,
                       unsigned short* __restrict__ Wt1, unsigned short* __restrict__ Wt2,
                       int* __restrict__ deg, int N, float* __restrict__ g,
                       const int* __restrict__ batch, int* __restrict__ start) {
  int t = blockIdx.x * 256 + threadIdx.x;
  if (t < N) deg[t] = 0;
  if (t < NG * D) g[t] = 0.f;
  if (t < NG) {          // graph boundary binary search (batch is sorted)
    int lo = 0, hi = N;
    while (lo < hi) {
      int mid = (lo + hi) >> 1;
      if (batch[mid] < t) lo = mid + 1; else hi = mid;
    }
    start[t] = lo;
    if (t == 0) start[NG] = N;
  }
  if (t >= 3 * 128 * 128) return;
  int l = t >> 14, k = (t >> 7) & 127, n = t & 127;
  int o = (l << 14) + (n << 7) + k;
  Wt1[o] = f2bf(W1[t]);
  Wt2[o] = f2bf(W2[t]);
}

// ---------------- CSR build: single cooperative kernel ---------------------
// hist -> block scan -> bsum scan -> offsets -> scatter, with grid syncs.
// __threadfence() around each sync: per-XCD L2s are non-coherent, plain
// stores (deg/bsum/pos) must be flushed to device scope before readers on
// other XCDs touch them (guide G16). 512 blocks x 256 thr, tiny LDS/VGPR ->
// residency validated by the cooperative-launch API.

__global__ __launch_bounds__(256) void csr_build(
    const int* __restrict__ src, const int* __restrict__ dst,
    int* __restrict__ deg, int* __restrict__ rowptr, int* __restrict__ pos,
    int* __restrict__ bsum, int* __restrict__ csr_src, int N, int E) {
  cg::grid_group grid = cg::this_grid();
  __shared__ int sh[256];
  int tid  = threadIdx.x;
  int gtid = blockIdx.x * 256 + tid;
  const int nth = CSR_BLOCKS * 256;   // 131072 >= N

  // phase 1: degree histogram (deg pre-zeroed by prep_w)
  for (int e = gtid; e < E; e += nth)
    atomicAdd(deg + dst[e], 1);
  __threadfence();
  grid.sync();

  // phase 2: block-local inclusive scan over this block's 256-elem window
  int v = (gtid < N) ? deg[gtid] : 0;
  sh[tid] = v;
  __syncthreads();
  for (int off = 1; off < 256; off <<= 1) {
    int x = (tid >= off) ? sh[tid - off] : 0;
    __syncthreads();
    sh[tid] += x;
    __syncthreads();
  }
  if (tid == 255) bsum[blockIdx.x] = sh[255];
  int local_ex = sh[tid] - v;          // exclusive prefix within block
  __threadfence();
  grid.sync();

  // phase 3: block 0 exclusive-scans bsum[512] (2 values per thread)
  if (blockIdx.x == 0) {
    int a = bsum[tid * 2], b = bsum[tid * 2 + 1];
    int pairsum = a + b;
    sh[tid] = pairsum;
    __syncthreads();
    for (int off = 1; off < 256; off <<= 1) {
      int x = (tid >= off) ? sh[tid - off] : 0;
      __syncthreads();
      sh[tid] += x;
      __syncthreads();
    }
    int ex = sh[tid] - pairsum;
    bsum[tid * 2]     = ex;
    bsum[tid * 2 + 1] = ex + a;
  }
  __threadfence();
  grid.sync();

  // phase 4: global offsets -> rowptr + pos
  if (gtid < N) {
    int val = local_ex + bsum[blockIdx.x];
    rowptr[gtid] = val;
    pos[gtid] = val;
  }
  if (gtid == 0) rowptr[N] = E;
  __threadfence();
  grid.sync();

  // phase 5: edge scatter
  for (int e = gtid; e < E; e += nth)
    csr_src[atomicAdd(pos + dst[e], 1)] = src[e];
}

// ---------------- gather aggregation: agg[i] = z[i] + sum neighbors --------
// ROOFLINED for this pattern (6 rounds of evidence): ~57us at ~3.6 TB/s
// post-L2 random-granule BW, invariant to ILP depth, lanes/node, occupancy
// and payload width (f32 512B rows = same time as bf16 256B => per-granule
// fixed cost; fp8 would gain nothing). NT hints: csr_src read-once loads and
// agg write-once stores bypass caches so they don't evict zb from L2.

template<bool IN_BF16>
__global__ __launch_bounds__(256) void gather_agg(const void* __restrict__ zin,
    const int* __restrict__ rowptr, const int* __restrict__ csr_src,
    unsigned short* __restrict__ agg, int N) {
  int t = blockIdx.x * 256 + threadIdx.x;
  int node = t >> 3;
  if (node >= N) return;
  int c = (t & 7) * 16;    // 16 elements per lane: 32B bf16 / 64B f32
  const float* zf = (const float*)zin;
  const unsigned short* zb = (const unsigned short*)zin;

  float acc[16];

  // self term
  if constexpr (IN_BF16) {
    const unsigned short* p = zb + (size_t)node * D + c;
    bf16x8 v0 = *(const bf16x8*)(p);
    bf16x8 v1 = *(const bf16x8*)(p + 8);
#pragma unroll
    for (int j = 0; j < 8; ++j) {
      acc[j]     = bf2f((unsigned short)v0[j]);
      acc[j + 8] = bf2f((unsigned short)v1[j]);
    }
  } else {
    const float* p = zf + (size_t)node * D + c;
    float4 v0 = *(const float4*)(p);
    float4 v1 = *(const float4*)(p + 4);
    float4 v2 = *(const float4*)(p + 8);
    float4 v3 = *(const float4*)(p + 12);
    acc[0]  = v0.x; acc[1]  = v0.y; acc[2]  = v0.z; acc[3]  = v0.w;
    acc[4]  = v1.x; acc[5]  = v1.y; acc[6]  = v1.z; acc[7]  = v1.w;
    acc[8]  = v2.x; acc[9]  = v2.y; acc[10] = v2.z; acc[11] = v2.w;
    acc[12] = v3.x; acc[13] = v3.y; acc[14] = v3.z; acc[15] = v3.w;
  }

  int e  = rowptr[node];
  int e1 = rowptr[node + 1];

  if constexpr (IN_BF16) {
    for (; e + 4 <= e1; e += 4) {
      int s0 = __builtin_nontemporal_load(csr_src + e + 0);
      int s1 = __builtin_nontemporal_load(csr_src + e + 1);
      int s2 = __builtin_nontemporal_load(csr_src + e + 2);
      int s3 = __builtin_nontemporal_load(csr_src + e + 3);
      const unsigned short* p0 = zb + (size_t)s0 * D + c;
      const unsigned short* p1 = zb + (size_t)s1 * D + c;
      const unsigned short* p2 = zb + (size_t)s2 * D + c;
      const unsigned short* p3 = zb + (size_t)s3 * D + c;
      bf16x8 a0 = *(const bf16x8*)(p0), a1 = *(const bf16x8*)(p0 + 8);
      bf16x8 b0 = *(const bf16x8*)(p1), b1 = *(const bf16x8*)(p1 + 8);
      bf16x8 c0 = *(const bf16x8*)(p2), c1 = *(const bf16x8*)(p2 + 8);
      bf16x8 d0 = *(const bf16x8*)(p3), d1 = *(const bf16x8*)(p3 + 8);
#pragma unroll
      for (int j = 0; j < 8; ++j) {
        acc[j]     += (bf2f((unsigned short)a0[j]) + bf2f((unsigned short)b0[j]))
                    + (bf2f((unsigned short)c0[j]) + bf2f((unsigned short)d0[j]));
        acc[j + 8] += (bf2f((unsigned short)a1[j]) + bf2f((unsigned short)b1[j]))
                    + (bf2f((unsigned short)c1[j]) + bf2f((unsigned short)d1[j]));
      }
    }
    if (e + 2 <= e1) {
      int s0 = __builtin_nontemporal_load(csr_src + e + 0);
      int s1 = __builtin_nontemporal_load(csr_src + e + 1);
      const unsigned short* p0 = zb + (size_t)s0 * D + c;
      const unsigned short* p1 = zb + (size_t)s1 * D + c;
      bf16x8 a0 = *(const bf16x8*)(p0), a1 = *(const bf16x8*)(p0 + 8);
      bf16x8 b0 = *(const bf16x8*)(p1), b1 = *(const bf16x8*)(p1 + 8);
#pragma unroll
      for (int j = 0; j < 8; ++j) {
        acc[j]     += bf2f((unsigned short)a0[j]) + bf2f((unsigned short)b0[j]);
        acc[j + 8] += bf2f((unsigned short)a1[j]) + bf2f((unsigned short)b1[j]);
      }
      e += 2;
    }
    if (e < e1) {
      int s0 = __builtin_nontemporal_load(csr_src + e);
      const unsigned short* p0 = zb + (size_t)s0 * D + c;
      bf16x8 a0 = *(const bf16x8*)(p0), a1 = *(const bf16x8*)(p0 + 8);
#pragma unroll
      for (int j = 0; j < 8; ++j) {
        acc[j]     += bf2f((unsigned short)a0[j]);
        acc[j + 8] += bf2f((unsigned short)a1[j]);
      }
    }
  } else {
    for (; e + 2 <= e1; e += 2) {
      int s0 = __builtin_nontemporal_load(csr_src + e + 0);
      int s1 = __builtin_nontemporal_load(csr_src + e + 1);
      const float* p0 = zf + (size_t)s0 * D + c;
      const float* p1 = zf + (size_t)s1 * D + c;
      float4 u0 = *(const float4*)(p0);
      float4 u1 = *(const float4*)(p0 + 4);
      float4 u2 = *(const float4*)(p0 + 8);
      float4 u3 = *(const float4*)(p0 + 12);
      float4 w0 = *(const float4*)(p1);
      float4 w1 = *(const float4*)(p1 + 4);
      float4 w2 = *(const float4*)(p1 + 8);
      float4 w3 = *(const float4*)(p1 + 12);
      acc[0]  += u0.x + w0.x; acc[1]  += u0.y + w0.y;
      acc[2]  += u0.z + w0.z; acc[3]  += u0.w + w0.w;
      acc[4]  += u1.x + w1.x; acc[5]  += u1.y + w1.y;
      acc[6]  += u1.z + w1.z; acc[7]  += u1.w + w1.w;
      acc[8]  += u2.x + w2.x; acc[9]  += u2.y + w2.y;
      acc[10] += u2.z + w2.z; acc[11] += u2.w + w2.w;
      acc[12] += u3.x + w3.x; acc[13] += u3.y + w3.y;
      acc[14] += u3.z + w3.z; acc[15] += u3.w + w3.w;
    }
    if (e < e1) {
      int s0 = __builtin_nontemporal_load(csr_src + e);
      const float* p0 = zf + (size_t)s0 * D + c;
      float4 u0 = *(const float4*)(p0);
      float4 u1 = *(const float4*)(p0 + 4);
      float4 u2 = *(const float4*)(p0 + 8);
      float4 u3 = *(const float4*)(p0 + 12);
      acc[0]  += u0.x; acc[1]  += u0.y; acc[2]  += u0.z; acc[3]  += u0.w;
      acc[4]  += u1.x; acc[5]  += u1.y; acc[6]  += u1.z; acc[7]  += u1.w;
      acc[8]  += u2.x; acc[9]  += u2.y; acc[10] += u2.z; acc[11] += u2.w;
      acc[12] += u3.x; acc[13] += u3.y; acc[14] += u3.z; acc[15] += u3.w;
    }
  }

  bf16x8 o0, o1;
#pragma unroll
  for (int j = 0; j < 8; ++j) {
    o0[j] = (short)f2bf(acc[j]);
    o1[j] = (short)f2bf(acc[j + 8]);
  }
  unsigned short* q = agg + (size_t)node * D + c;
  __builtin_nontemporal_store(o0, (bf16x8*)(q));
  __builtin_nontemporal_store(o1, (bf16x8*)(q + 8));
}

// ---------------- fused per-layer MLP: z = ReLU(ReLU(A@W1+b1)@W2+b2) -------
// R8 structure (unchanged -- near its BW floor): weights once per block
// (W1->reg, W2->LDS), 2 tiles of 128 rows, both tiles' A-fragments loaded
// up front, full 32-row warp tiles with 2-row-fragment B-reuse, warp-private
// hs (no barriers after the w2s one), staged 256B coalesced z stores.

template<bool LAST>
__global__ __launch_bounds__(256, 2) void gemm_fused(const unsigned short* __restrict__ A,
    const unsigned short* __restrict__ Wt1, const float* __restrict__ b1v,
    const unsigned short* __restrict__ Wt2, const float* __restrict__ b2v,
    unsigned short* __restrict__ Zb, float* __restrict__ Zf, int M, int nt) {
  __shared__ unsigned short w2s[128][136];
  __shared__ unsigned short hs[4][32][136];
  int tid  = threadIdx.x;
  int lane = tid & 63;
  int wid  = tid >> 6;
  int c16  = lane & 15;
  int kq   = lane >> 4;
  int koff = kq * 8;

  int tile0 = blockIdx.x * 2;
  int tile1 = tile0 + 1;

  // issue BOTH tiles' A-loads first (latency hidden under weight staging)
  bf16x8 aA[2][4], aB[2][4];
#pragma unroll
  for (int h = 0; h < 2; ++h) {
    int rowA = tile0 * 128 + wid * 32 + h * 16 + c16;
    rowA = rowA < M ? rowA : M - 1;
    int rowB = tile1 * 128 + wid * 32 + h * 16 + c16;
    rowB = rowB < M ? rowB : M - 1;
#pragma unroll
    for (int kk = 0; kk < 4; ++kk) {
      aA[h][kk] = *(const bf16x8*)(A + (size_t)rowA * D + kk * 32 + koff);
      aB[h][kk] = *(const bf16x8*)(A + (size_t)rowB * D + kk * 32 + koff);
    }
  }

  // stage W2 -> LDS (coalesced 16B chunks; 2048 chunks / 256 threads = 8 ea)
#pragma unroll
  for (int i = 0; i < 8; ++i) {
    int chunk = i * 256 + tid;
    int row = chunk >> 4, k16 = chunk & 15;
    *(bf16x8*)&w2s[row][k16 * 8] = *(const bf16x8*)(Wt2 + (size_t)row * D + k16 * 8);
  }

  // hoist W1 fragments + both biases (once per block)
  bf16x8 bf1[8][4];
  float  bb1[8], bb2[8];
#pragma unroll
  for (int fc = 0; fc < 8; ++fc) {
    int col = fc * 16 + c16;
    bb1[fc] = b1v[col];
    bb2[fc] = b2v[col];
#pragma unroll
    for (int kk = 0; kk < 4; ++kk)
      bf1[fc][kk] = *(const bf16x8*)(Wt1 + (size_t)col * D + kk * 32 + koff);
  }

  __syncthreads();   // w2s ready

  auto TILE = [&](const bf16x8 (&a)[2][4], int tile) {
    int rb = tile * 128 + wid * 32;
    // GEMM1 (full 32-row warp tile) -> hs; warp-private, in-wave ordering
#pragma unroll
    for (int fc = 0; fc < 8; ++fc) {
      f32x4 acc0 = {0.f, 0.f, 0.f, 0.f};
      f32x4 acc1 = {0.f, 0.f, 0.f, 0.f};
#pragma unroll
      for (int kk = 0; kk < 4; ++kk) {
        acc0 = __builtin_amdgcn_mfma_f32_16x16x32_bf16(a[0][kk], bf1[fc][kk], acc0, 0, 0, 0);
        acc1 = __builtin_amdgcn_mfma_f32_16x16x32_bf16(a[1][kk], bf1[fc][kk], acc1, 0, 0, 0);
      }
      int col = fc * 16 + c16;
#pragma unroll
      for (int r = 0; r < 4; ++r) {
        hs[wid][kq * 4 + r][col]      = f2bf(fmaxf(acc0[r] + bb1[fc], 0.f));
        hs[wid][kq * 4 + r + 16][col] = f2bf(fmaxf(acc1[r] + bb1[fc], 0.f));
      }
    }
    bf16x8 a2[2][4];
#pragma unroll
    for (int fr = 0; fr < 2; ++fr)
#pragma unroll
      for (int kk = 0; kk < 4; ++kk)
        a2[fr][kk] = *(const bf16x8*)&hs[wid][fr * 16 + c16][kk * 32 + koff];
    // GEMM2 (B from LDS)
#pragma unroll
    for (int fc = 0; fc < 8; ++fc) {
      f32x4 acc0 = {0.f, 0.f, 0.f, 0.f};
      f32x4 acc1 = {0.f, 0.f, 0.f, 0.f};
      int col = fc * 16 + c16;
#pragma unroll
      for (int kk = 0; kk < 4; ++kk) {
        bf16x8 b = *(const bf16x8*)&w2s[col][kk * 32 + koff];
        acc0 = __builtin_amdgcn_mfma_f32_16x16x32_bf16(a2[0][kk], b, acc0, 0, 0, 0);
        acc1 = __builtin_amdgcn_mfma_f32_16x16x32_bf16(a2[1][kk], b, acc1, 0, 0, 0);
      }
      if constexpr (LAST) {
#pragma unroll
        for (int r = 0; r < 4; ++r) {
          int row0 = rb + kq * 4 + r;
          if (row0 < M) Zf[(size_t)row0 * D + col] = fmaxf(acc0[r] + bb2[fc], 0.f);
          int row1 = row0 + 16;
          if (row1 < M) Zf[(size_t)row1 * D + col] = fmaxf(acc1[r] + bb2[fc], 0.f);
        }
      } else {
        // a2 already in registers -> safe to overwrite hs
#pragma unroll
        for (int r = 0; r < 4; ++r) {
          hs[wid][kq * 4 + r][col]      = f2bf(fmaxf(acc0[r] + bb2[fc], 0.f));
          hs[wid][kq * 4 + r + 16][col] = f2bf(fmaxf(acc1[r] + bb2[fc], 0.f));
        }
      }
    }
    if constexpr (!LAST) {
      // staged coalesced stores: per i, 4 rows x 256B contiguous segments
#pragma unroll
      for (int i = 0; i < 8; ++i) {
        int rl = i * 4 + kq;
        bf16x8 v = *(const bf16x8*)&hs[wid][rl][c16 * 8];
        int row = rb + rl;
        if (row < M)
          *(bf16x8*)(Zb + (size_t)row * D + c16 * 8) = v;
      }
    }
  };

  TILE(aA, tile0);
  if (tile1 < nt) TILE(aB, tile1);
}

// ---------------- pooling: bounds (in prep_w) + streaming mean -------------
// Each chunk atomically adds its partial sum pre-scaled by 1/len -> the
// divide pass disappears (g zeroed in prep_w; empty graphs stay 0).

#define PCHUNKS 8
__global__ __launch_bounds__(128) void pool_mean(const float* __restrict__ z,
    const int* __restrict__ start, float* __restrict__ g) {
  int gid   = blockIdx.x >> 3;
  int chunk = blockIdx.x & (PCHUNKS - 1);
  int col = threadIdx.x;
  int s = start[gid], epos = start[gid + 1];
  int len = epos - s;
  if (len <= 0) return;
  float inv = 1.0f / (float)len;
  int per = (len + PCHUNKS - 1) / PCHUNKS;
  int r0 = s + chunk * per;
  int r1 = min(r0 + per, epos);
  if (r0 >= r1) return;
  float a0 = 0.f, a1 = 0.f, a2 = 0.f, a3 = 0.f;
  int i = r0;
  for (; i + 4 <= r1; i += 4) {
    a0 += z[(size_t)(i + 0) * D + col];
    a1 += z[(size_t)(i + 1) * D + col];
    a2 += z[(size_t)(i + 2) * D + col];
    a3 += z[(size_t)(i + 3) * D + col];
  }
  for (; i < r1; ++i) a0 += z[(size_t)i * D + col];
  atomicAdd(g + (size_t)gid * D + col, ((a0 + a1) + (a2 + a3)) * inv);
}

extern "C" void kernel_launch(void* const* d_in, const int* in_sizes, int n_in,
                              void* d_out, int out_size, void* d_ws, size_t ws_size,
                              hipStream_t stream) {
  const float* x     = (const float*)d_in[0];
  const int*   ei    = (const int*)d_in[1];
  const int*   batch = (const int*)d_in[2];
  const float* W1    = (const float*)d_in[3];
  const float* b1    = (const float*)d_in[4];
  const float* W2    = (const float*)d_in[5];
  const float* b2    = (const float*)d_in[6];

  const int N = in_sizes[0] / D;       // 100000
  const int E = in_sizes[1] / 2;       // 640000
  const int* src = ei;
  const int* dst = ei + E;

  float* zout = (float*)d_out;
  float* g    = zout + (size_t)N * D;

  // workspace layout
  char* w = (char*)d_ws;
  unsigned short* agg     = (unsigned short*)w;    w += (size_t)N * D * 2;
  unsigned short* zb      = (unsigned short*)w;    w += (size_t)N * D * 2;
  unsigned short* Wt1     = (unsigned short*)w;    w += 3 * 16384 * 2;
  unsigned short* Wt2     = (unsigned short*)w;    w += 3 * 16384 * 2;
  int*            start   = (int*)w;               w += (NG + 4) * 4;
  int*            deg     = (int*)w;               w += (size_t)N * 4;
  int*            rowptr  = (int*)w;               w += (size_t)(N + 4) * 4;
  int*            pos     = (int*)w;               w += (size_t)N * 4;
  int*            bsum    = (int*)w;               w += CSR_BLOCKS * 4;
  int*            csr_src = (int*)w;               w += (size_t)E * 4;

  // weight prep + deg/g zero + pool bounds (folded)
  int prep_threads = (3 * 128 * 128 > N) ? 3 * 128 * 128 : N;
  prep_w<<<(prep_threads + 255) / 256, 256, 0, stream>>>(W1, W2, Wt1, Wt2, deg, N, g,
                                                         batch, start);

  // CSR build: one cooperative kernel (hist + scan + scatter)
  {
    const int* src_ = src;
    const int* dst_ = dst;
    int N_ = N, E_ = E;
    void* args[] = {(void*)&src_, (void*)&dst_, (void*)&deg, (void*)&rowptr,
                    (void*)&pos, (void*)&bsum, (void*)&csr_src,
                    (void*)&N_, (void*)&E_};
    hipLaunchCooperativeKernel((void*)csr_build, dim3(CSR_BLOCKS), dim3(256),
                               args, 0, stream);
  }

  const int gather_blocks = (int)(((size_t)N * 8 + 255) / 256);   // 3125
  const int nt            = (N + 127) / 128;                      // 782 tiles
  const int gemm_blocks   = (nt + 1) / 2;                         // 391

  // layer 0 (input f32 x)
  gather_agg<false><<<gather_blocks, 256, 0, stream>>>(x, rowptr, csr_src, agg, N);
  gemm_fused<false><<<gemm_blocks, 256, 0, stream>>>(agg, Wt1, b1, Wt2, b2, zb, zout, N, nt);
  // layer 1
  gather_agg<true><<<gather_blocks, 256, 0, stream>>>(zb, rowptr, csr_src, agg, N);
  gemm_fused<false><<<gemm_blocks, 256, 0, stream>>>(agg, Wt1 + 16384, b1 + 128,
                                                     Wt2 + 16384, b2 + 128, zb, zout, N, nt);
  // layer 2 (writes f32 zout)
  gather_agg<true><<<gather_blocks, 256, 0, stream>>>(zb, rowptr, csr_src, agg, N);
  gemm_fused<true><<<gemm_blocks, 256, 0, stream>>>(agg, Wt1 + 32768, b1 + 256,
                                                    Wt2 + 32768, b2 + 256, zb, zout, N, nt);

  pool_mean<<<NG * PCHUNKS, 128, 0, stream>>>(zout, start, g);
}

// Round 10
// 284.612 us; speedup vs baseline: 2.2623x; 2.2623x over previous
//
#include <hip/hip_runtime.h>
#include <hip/hip_bf16.h>

#define D 128
#define NG 128

typedef __attribute__((ext_vector_type(8))) short bf16x8;
typedef __attribute__((ext_vector_type(4))) float f32x4;

__device__ inline unsigned short f2bf(float f) {
  union { float f; unsigned u; } c; c.f = f;
  unsigned u = c.u;
  return (unsigned short)((u + 0x7FFFu + ((u >> 16) & 1u)) >> 16);  // RNE
}
__device__ inline float bf2f(unsigned short b) {
  union { unsigned u; float f; } c; c.u = ((unsigned)b) << 16;
  return c.f;
}

// Transpose + bf16-convert weights: Wt[l][n][k] = bf16(W[l][k][n]).
// Also zeroes deg[]/g[] and computes pool graph bounds (folded launches).
__global__ void prep_w(const float* __restrict__ W1, const float* __restrict__ W2,
                       unsigned short* __restrict__ Wt1, unsigned short* __restrict__ Wt2,
                       int* __restrict__ deg, int N, float* __restrict__ g,
                       const int* __restrict__ batch, int* __restrict__ start) {
  int t = blockIdx.x * 256 + threadIdx.x;
  if (t < N) deg[t] = 0;
  if (t < NG * D) g[t] = 0.f;
  if (t < NG) {          // graph boundary binary search (batch is sorted)
    int lo = 0, hi = N;
    while (lo < hi) {
      int mid = (lo + hi) >> 1;
      if (batch[mid] < t) lo = mid + 1; else hi = mid;
    }
    start[t] = lo;
    if (t == 0) start[NG] = N;
  }
  if (t >= 3 * 128 * 128) return;
  int l = t >> 14, k = (t >> 7) & 127, n = t & 127;
  int o = (l << 14) + (n << 7) + k;
  Wt1[o] = f2bf(W1[t]);
  Wt2[o] = f2bf(W2[t]);
}

// ---------------- CSR build ------------------------------------------------
// Five small stream-ordered kernels. R9 measured the alternative: one
// cooperative kernel with 4 grid.sync()s ran 410us (~100us per grid-wide
// sync across 8 non-coherent XCD L2s). Stream-ordered launch boundaries ARE
// the cheap grid barrier on this chip (~3us each).

__global__ void hist_deg(const int* __restrict__ dst, int* __restrict__ deg, int E) {
  int e = blockIdx.x * 256 + threadIdx.x;
  if (e < E) atomicAdd(deg + dst[e], 1);
}

__global__ __launch_bounds__(256) void scan1(const int* __restrict__ deg,
    int* __restrict__ rowptr, int* __restrict__ bsum, int n) {
  __shared__ int sh[256];
  int tid = threadIdx.x;
  int idx = blockIdx.x * 1024 + tid * 4;
  int v[4], tsum = 0;
#pragma unroll
  for (int j = 0; j < 4; ++j) { v[j] = (idx + j < n) ? deg[idx + j] : 0; tsum += v[j]; }
  sh[tid] = tsum;
  __syncthreads();
  for (int off = 1; off < 256; off <<= 1) {
    int x = (tid >= off) ? sh[tid - off] : 0;
    __syncthreads();
    sh[tid] += x;
    __syncthreads();
  }
  if (tid == 255) bsum[blockIdx.x] = sh[255];
  int run = sh[tid] - tsum;
#pragma unroll
  for (int j = 0; j < 4; ++j) { if (idx + j < n) rowptr[idx + j] = run; run += v[j]; }
}

// single 128-thread block scan of per-block sums (nb <= 128)
__global__ __launch_bounds__(128) void scan2(int* __restrict__ bsum, int nb) {
  __shared__ int sh[128];
  int tid = threadIdx.x;
  int v = (tid < nb) ? bsum[tid] : 0;
  sh[tid] = v;
  __syncthreads();
  for (int off = 1; off < 128; off <<= 1) {
    int x = (tid >= off) ? sh[tid - off] : 0;
    __syncthreads();
    sh[tid] += x;
    __syncthreads();
  }
  if (tid < nb) bsum[tid] = sh[tid] - v;
}

__global__ void scan3(int* __restrict__ rowptr, int* __restrict__ pos,
                      const int* __restrict__ bsum, int n, int E) {
  int t = blockIdx.x * 256 + threadIdx.x;
  if (t < n) {
    int v = rowptr[t] + bsum[t >> 10];
    rowptr[t] = v;
    pos[t] = v;
  }
  if (t == 0) rowptr[n] = E;
}

__global__ void edge_scatter(const int* __restrict__ src, const int* __restrict__ dst,
                             int* __restrict__ pos, int* __restrict__ csr_src, int E) {
  int e = blockIdx.x * 256 + threadIdx.x;
  if (e >= E) return;
  int idx = atomicAdd(pos + dst[e], 1);
  csr_src[idx] = src[e];
}

// ---------------- gather aggregation: agg[i] = z[i] + sum neighbors --------
// ROOFLINED for this pattern (6 rounds of evidence): ~57us at ~3.6 TB/s
// post-L2 random-granule BW, invariant to ILP depth, lanes/node, occupancy
// and payload width (f32 512B rows = same time as bf16 256B => per-granule
// fixed cost; fp8 would gain nothing). NT hints: csr_src read-once loads and
// agg write-once stores bypass caches so they don't evict zb from L2.

template<bool IN_BF16>
__global__ __launch_bounds__(256) void gather_agg(const void* __restrict__ zin,
    const int* __restrict__ rowptr, const int* __restrict__ csr_src,
    unsigned short* __restrict__ agg, int N) {
  int t = blockIdx.x * 256 + threadIdx.x;
  int node = t >> 3;
  if (node >= N) return;
  int c = (t & 7) * 16;    // 16 elements per lane: 32B bf16 / 64B f32
  const float* zf = (const float*)zin;
  const unsigned short* zb = (const unsigned short*)zin;

  float acc[16];

  // self term
  if constexpr (IN_BF16) {
    const unsigned short* p = zb + (size_t)node * D + c;
    bf16x8 v0 = *(const bf16x8*)(p);
    bf16x8 v1 = *(const bf16x8*)(p + 8);
#pragma unroll
    for (int j = 0; j < 8; ++j) {
      acc[j]     = bf2f((unsigned short)v0[j]);
      acc[j + 8] = bf2f((unsigned short)v1[j]);
    }
  } else {
    const float* p = zf + (size_t)node * D + c;
    float4 v0 = *(const float4*)(p);
    float4 v1 = *(const float4*)(p + 4);
    float4 v2 = *(const float4*)(p + 8);
    float4 v3 = *(const float4*)(p + 12);
    acc[0]  = v0.x; acc[1]  = v0.y; acc[2]  = v0.z; acc[3]  = v0.w;
    acc[4]  = v1.x; acc[5]  = v1.y; acc[6]  = v1.z; acc[7]  = v1.w;
    acc[8]  = v2.x; acc[9]  = v2.y; acc[10] = v2.z; acc[11] = v2.w;
    acc[12] = v3.x; acc[13] = v3.y; acc[14] = v3.z; acc[15] = v3.w;
  }

  int e  = rowptr[node];
  int e1 = rowptr[node + 1];

  if constexpr (IN_BF16) {
    for (; e + 4 <= e1; e += 4) {
      int s0 = __builtin_nontemporal_load(csr_src + e + 0);
      int s1 = __builtin_nontemporal_load(csr_src + e + 1);
      int s2 = __builtin_nontemporal_load(csr_src + e + 2);
      int s3 = __builtin_nontemporal_load(csr_src + e + 3);
      const unsigned short* p0 = zb + (size_t)s0 * D + c;
      const unsigned short* p1 = zb + (size_t)s1 * D + c;
      const unsigned short* p2 = zb + (size_t)s2 * D + c;
      const unsigned short* p3 = zb + (size_t)s3 * D + c;
      bf16x8 a0 = *(const bf16x8*)(p0), a1 = *(const bf16x8*)(p0 + 8);
      bf16x8 b0 = *(const bf16x8*)(p1), b1 = *(const bf16x8*)(p1 + 8);
      bf16x8 c0 = *(const bf16x8*)(p2), c1 = *(const bf16x8*)(p2 + 8);
      bf16x8 d0 = *(const bf16x8*)(p3), d1 = *(const bf16x8*)(p3 + 8);
#pragma unroll
      for (int j = 0; j < 8; ++j) {
        acc[j]     += (bf2f((unsigned short)a0[j]) + bf2f((unsigned short)b0[j]))
                    + (bf2f((unsigned short)c0[j]) + bf2f((unsigned short)d0[j]));
        acc[j + 8] += (bf2f((unsigned short)a1[j]) + bf2f((unsigned short)b1[j]))
                    + (bf2f((unsigned short)c1[j]) + bf2f((unsigned short)d1[j]));
      }
    }
    if (e + 2 <= e1) {
      int s0 = __builtin_nontemporal_load(csr_src + e + 0);
      int s1 = __builtin_nontemporal_load(csr_src + e + 1);
      const unsigned short* p0 = zb + (size_t)s0 * D + c;
      const unsigned short* p1 = zb + (size_t)s1 * D + c;
      bf16x8 a0 = *(const bf16x8*)(p0), a1 = *(const bf16x8*)(p0 + 8);
      bf16x8 b0 = *(const bf16x8*)(p1), b1 = *(const bf16x8*)(p1 + 8);
#pragma unroll
      for (int j = 0; j < 8; ++j) {
        acc[j]     += bf2f((unsigned short)a0[j]) + bf2f((unsigned short)b0[j]);
        acc[j + 8] += bf2f((unsigned short)a1[j]) + bf2f((unsigned short)b1[j]);
      }
      e += 2;
    }
    if (e < e1) {
      int s0 = __builtin_nontemporal_load(csr_src + e);
      const unsigned short* p0 = zb + (size_t)s0 * D + c;
      bf16x8 a0 = *(const bf16x8*)(p0), a1 = *(const bf16x8*)(p0 + 8);
#pragma unroll
      for (int j = 0; j < 8; ++j) {
        acc[j]     += bf2f((unsigned short)a0[j]);
        acc[j + 8] += bf2f((unsigned short)a1[j]);
      }
    }
  } else {
    for (; e + 2 <= e1; e += 2) {
      int s0 = __builtin_nontemporal_load(csr_src + e + 0);
      int s1 = __builtin_nontemporal_load(csr_src + e + 1);
      const float* p0 = zf + (size_t)s0 * D + c;
      const float* p1 = zf + (size_t)s1 * D + c;
      float4 u0 = *(const float4*)(p0);
      float4 u1 = *(const float4*)(p0 + 4);
      float4 u2 = *(const float4*)(p0 + 8);
      float4 u3 = *(const float4*)(p0 + 12);
      float4 w0 = *(const float4*)(p1);
      float4 w1 = *(const float4*)(p1 + 4);
      float4 w2 = *(const float4*)(p1 + 8);
      float4 w3 = *(const float4*)(p1 + 12);
      acc[0]  += u0.x + w0.x; acc[1]  += u0.y + w0.y;
      acc[2]  += u0.z + w0.z; acc[3]  += u0.w + w0.w;
      acc[4]  += u1.x + w1.x; acc[5]  += u1.y + w1.y;
      acc[6]  += u1.z + w1.z; acc[7]  += u1.w + w1.w;
      acc[8]  += u2.x + w2.x; acc[9]  += u2.y + w2.y;
      acc[10] += u2.z + w2.z; acc[11] += u2.w + w2.w;
      acc[12] += u3.x + w3.x; acc[13] += u3.y + w3.y;
      acc[14] += u3.z + w3.z; acc[15] += u3.w + w3.w;
    }
    if (e < e1) {
      int s0 = __builtin_nontemporal_load(csr_src + e);
      const float* p0 = zf + (size_t)s0 * D + c;
      float4 u0 = *(const float4*)(p0);
      float4 u1 = *(const float4*)(p0 + 4);
      float4 u2 = *(const float4*)(p0 + 8);
      float4 u3 = *(const float4*)(p0 + 12);
      acc[0]  += u0.x; acc[1]  += u0.y; acc[2]  += u0.z; acc[3]  += u0.w;
      acc[4]  += u1.x; acc[5]  += u1.y; acc[6]  += u1.z; acc[7]  += u1.w;
      acc[8]  += u2.x; acc[9]  += u2.y; acc[10] += u2.z; acc[11] += u2.w;
      acc[12] += u3.x; acc[13] += u3.y; acc[14] += u3.z; acc[15] += u3.w;
    }
  }

  bf16x8 o0, o1;
#pragma unroll
  for (int j = 0; j < 8; ++j) {
    o0[j] = (short)f2bf(acc[j]);
    o1[j] = (short)f2bf(acc[j + 8]);
  }
  unsigned short* q = agg + (size_t)node * D + c;
  __builtin_nontemporal_store(o0, (bf16x8*)(q));
  __builtin_nontemporal_store(o1, (bf16x8*)(q + 8));
}

// ---------------- fused per-layer MLP: z = ReLU(ReLU(A@W1+b1)@W2+b2) -------
// R8 structure (near its BW floor): weights once per block (W1->reg,
// W2->LDS), 2 tiles of 128 rows, both tiles' A-fragments loaded up front,
// full 32-row warp tiles with 2-row-fragment B-reuse, warp-private hs
// (no barriers after the w2s one), staged 256B coalesced z stores.

template<bool LAST>
__global__ __launch_bounds__(256, 2) void gemm_fused(const unsigned short* __restrict__ A,
    const unsigned short* __restrict__ Wt1, const float* __restrict__ b1v,
    const unsigned short* __restrict__ Wt2, const float* __restrict__ b2v,
    unsigned short* __restrict__ Zb, float* __restrict__ Zf, int M, int nt) {
  __shared__ unsigned short w2s[128][136];
  __shared__ unsigned short hs[4][32][136];
  int tid  = threadIdx.x;
  int lane = tid & 63;
  int wid  = tid >> 6;
  int c16  = lane & 15;
  int kq   = lane >> 4;
  int koff = kq * 8;

  int tile0 = blockIdx.x * 2;
  int tile1 = tile0 + 1;

  // issue BOTH tiles' A-loads first (latency hidden under weight staging)
  bf16x8 aA[2][4], aB[2][4];
#pragma unroll
  for (int h = 0; h < 2; ++h) {
    int rowA = tile0 * 128 + wid * 32 + h * 16 + c16;
    rowA = rowA < M ? rowA : M - 1;
    int rowB = tile1 * 128 + wid * 32 + h * 16 + c16;
    rowB = rowB < M ? rowB : M - 1;
#pragma unroll
    for (int kk = 0; kk < 4; ++kk) {
      aA[h][kk] = *(const bf16x8*)(A + (size_t)rowA * D + kk * 32 + koff);
      aB[h][kk] = *(const bf16x8*)(A + (size_t)rowB * D + kk * 32 + koff);
    }
  }

  // stage W2 -> LDS (coalesced 16B chunks; 2048 chunks / 256 threads = 8 ea)
#pragma unroll
  for (int i = 0; i < 8; ++i) {
    int chunk = i * 256 + tid;
    int row = chunk >> 4, k16 = chunk & 15;
    *(bf16x8*)&w2s[row][k16 * 8] = *(const bf16x8*)(Wt2 + (size_t)row * D + k16 * 8);
  }

  // hoist W1 fragments + both biases (once per block)
  bf16x8 bf1[8][4];
  float  bb1[8], bb2[8];
#pragma unroll
  for (int fc = 0; fc < 8; ++fc) {
    int col = fc * 16 + c16;
    bb1[fc] = b1v[col];
    bb2[fc] = b2v[col];
#pragma unroll
    for (int kk = 0; kk < 4; ++kk)
      bf1[fc][kk] = *(const bf16x8*)(Wt1 + (size_t)col * D + kk * 32 + koff);
  }

  __syncthreads();   // w2s ready

  auto TILE = [&](const bf16x8 (&a)[2][4], int tile) {
    int rb = tile * 128 + wid * 32;
    // GEMM1 (full 32-row warp tile) -> hs; warp-private, in-wave ordering
#pragma unroll
    for (int fc = 0; fc < 8; ++fc) {
      f32x4 acc0 = {0.f, 0.f, 0.f, 0.f};
      f32x4 acc1 = {0.f, 0.f, 0.f, 0.f};
#pragma unroll
      for (int kk = 0; kk < 4; ++kk) {
        acc0 = __builtin_amdgcn_mfma_f32_16x16x32_bf16(a[0][kk], bf1[fc][kk], acc0, 0, 0, 0);
        acc1 = __builtin_amdgcn_mfma_f32_16x16x32_bf16(a[1][kk], bf1[fc][kk], acc1, 0, 0, 0);
      }
      int col = fc * 16 + c16;
#pragma unroll
      for (int r = 0; r < 4; ++r) {
        hs[wid][kq * 4 + r][col]      = f2bf(fmaxf(acc0[r] + bb1[fc], 0.f));
        hs[wid][kq * 4 + r + 16][col] = f2bf(fmaxf(acc1[r] + bb1[fc], 0.f));
      }
    }
    bf16x8 a2[2][4];
#pragma unroll
    for (int fr = 0; fr < 2; ++fr)
#pragma unroll
      for (int kk = 0; kk < 4; ++kk)
        a2[fr][kk] = *(const bf16x8*)&hs[wid][fr * 16 + c16][kk * 32 + koff];
    // GEMM2 (B from LDS)
#pragma unroll
    for (int fc = 0; fc < 8; ++fc) {
      f32x4 acc0 = {0.f, 0.f, 0.f, 0.f};
      f32x4 acc1 = {0.f, 0.f, 0.f, 0.f};
      int col = fc * 16 + c16;
#pragma unroll
      for (int kk = 0; kk < 4; ++kk) {
        bf16x8 b = *(const bf16x8*)&w2s[col][kk * 32 + koff];
        acc0 = __builtin_amdgcn_mfma_f32_16x16x32_bf16(a2[0][kk], b, acc0, 0, 0, 0);
        acc1 = __builtin_amdgcn_mfma_f32_16x16x32_bf16(a2[1][kk], b, acc1, 0, 0, 0);
      }
      if constexpr (LAST) {
#pragma unroll
        for (int r = 0; r < 4; ++r) {
          int row0 = rb + kq * 4 + r;
          if (row0 < M) Zf[(size_t)row0 * D + col] = fmaxf(acc0[r] + bb2[fc], 0.f);
          int row1 = row0 + 16;
          if (row1 < M) Zf[(size_t)row1 * D + col] = fmaxf(acc1[r] + bb2[fc], 0.f);
        }
      } else {
        // a2 already in registers -> safe to overwrite hs
#pragma unroll
        for (int r = 0; r < 4; ++r) {
          hs[wid][kq * 4 + r][col]      = f2bf(fmaxf(acc0[r] + bb2[fc], 0.f));
          hs[wid][kq * 4 + r + 16][col] = f2bf(fmaxf(acc1[r] + bb2[fc], 0.f));
        }
      }
    }
    if constexpr (!LAST) {
      // staged coalesced stores: per i, 4 rows x 256B contiguous segments
#pragma unroll
      for (int i = 0; i < 8; ++i) {
        int rl = i * 4 + kq;
        bf16x8 v = *(const bf16x8*)&hs[wid][rl][c16 * 8];
        int row = rb + rl;
        if (row < M)
          *(bf16x8*)(Zb + (size_t)row * D + c16 * 8) = v;
      }
    }
  };

  TILE(aA, tile0);
  if (tile1 < nt) TILE(aB, tile1);
}

// ---------------- pooling: bounds (in prep_w) + streaming mean -------------
// Each chunk atomically adds its partial sum pre-scaled by 1/len -> no
// divide pass (g zeroed in prep_w; empty graphs stay 0).

#define PCHUNKS 8
__global__ __launch_bounds__(128) void pool_mean(const float* __restrict__ z,
    const int* __restrict__ start, float* __restrict__ g) {
  int gid   = blockIdx.x >> 3;
  int chunk = blockIdx.x & (PCHUNKS - 1);
  int col = threadIdx.x;
  int s = start[gid], epos = start[gid + 1];
  int len = epos - s;
  if (len <= 0) return;
  float inv = 1.0f / (float)len;
  int per = (len + PCHUNKS - 1) / PCHUNKS;
  int r0 = s + chunk * per;
  int r1 = min(r0 + per, epos);
  if (r0 >= r1) return;
  float a0 = 0.f, a1 = 0.f, a2 = 0.f, a3 = 0.f;
  int i = r0;
  for (; i + 4 <= r1; i += 4) {
    a0 += z[(size_t)(i + 0) * D + col];
    a1 += z[(size_t)(i + 1) * D + col];
    a2 += z[(size_t)(i + 2) * D + col];
    a3 += z[(size_t)(i + 3) * D + col];
  }
  for (; i < r1; ++i) a0 += z[(size_t)i * D + col];
  atomicAdd(g + (size_t)gid * D + col, ((a0 + a1) + (a2 + a3)) * inv);
}

extern "C" void kernel_launch(void* const* d_in, const int* in_sizes, int n_in,
                              void* d_out, int out_size, void* d_ws, size_t ws_size,
                              hipStream_t stream) {
  const float* x     = (const float*)d_in[0];
  const int*   ei    = (const int*)d_in[1];
  const int*   batch = (const int*)d_in[2];
  const float* W1    = (const float*)d_in[3];
  const float* b1    = (const float*)d_in[4];
  const float* W2    = (const float*)d_in[5];
  const float* b2    = (const float*)d_in[6];

  const int N = in_sizes[0] / D;       // 100000
  const int E = in_sizes[1] / 2;       // 640000
  const int* src = ei;
  const int* dst = ei + E;

  float* zout = (float*)d_out;
  float* g    = zout + (size_t)N * D;

  // workspace layout
  char* w = (char*)d_ws;
  unsigned short* agg     = (unsigned short*)w;    w += (size_t)N * D * 2;
  unsigned short* zb      = (unsigned short*)w;    w += (size_t)N * D * 2;
  unsigned short* Wt1     = (unsigned short*)w;    w += 3 * 16384 * 2;
  unsigned short* Wt2     = (unsigned short*)w;    w += 3 * 16384 * 2;
  int*            start   = (int*)w;               w += (NG + 4) * 4;
  int*            deg     = (int*)w;               w += (size_t)N * 4;
  int*            rowptr  = (int*)w;               w += (size_t)(N + 4) * 4;
  int*            pos     = (int*)w;               w += (size_t)N * 4;
  int*            bsum    = (int*)w;               w += 128 * 4;
  int*            csr_src = (int*)w;               w += (size_t)E * 4;

  const int nb = (N + 1023) / 1024;   // 98 <= 128

  // weight prep + deg/g zero + pool bounds (folded)
  int prep_threads = (3 * 128 * 128 > N) ? 3 * 128 * 128 : N;
  prep_w<<<(prep_threads + 255) / 256, 256, 0, stream>>>(W1, W2, Wt1, Wt2, deg, N, g,
                                                         batch, start);

  // CSR build (five small stream-ordered kernels -- see comment above)
  hist_deg<<<(E + 255) / 256, 256, 0, stream>>>(dst, deg, E);
  scan1<<<nb, 256, 0, stream>>>(deg, rowptr, bsum, N);
  scan2<<<1, 128, 0, stream>>>(bsum, nb);
  scan3<<<(N + 255) / 256, 256, 0, stream>>>(rowptr, pos, bsum, N, E);
  edge_scatter<<<(E + 255) / 256, 256, 0, stream>>>(src, dst, pos, csr_src, E);

  const int gather_blocks = (int)(((size_t)N * 8 + 255) / 256);   // 3125
  const int nt            = (N + 127) / 128;                      // 782 tiles
  const int gemm_blocks   = (nt + 1) / 2;                         // 391

  // layer 0 (input f32 x)
  gather_agg<false><<<gather_blocks, 256, 0, stream>>>(x, rowptr, csr_src, agg, N);
  gemm_fused<false><<<gemm_blocks, 256, 0, stream>>>(agg, Wt1, b1, Wt2, b2, zb, zout, N, nt);
  // layer 1
  gather_agg<true><<<gather_blocks, 256, 0, stream>>>(zb, rowptr, csr_src, agg, N);
  gemm_fused<false><<<gemm_blocks, 256, 0, stream>>>(agg, Wt1 + 16384, b1 + 128,
                                                     Wt2 + 16384, b2 + 128, zb, zout, N, nt);
  // layer 2 (writes f32 zout)
  gather_agg<true><<<gather_blocks, 256, 0, stream>>>(zb, rowptr, csr_src, agg, N);
  gemm_fused<true><<<gemm_blocks, 256, 0, stream>>>(agg, Wt1 + 32768, b1 + 256,
                                                    Wt2 + 32768, b2 + 256, zb, zout, N, nt);

  pool_mean<<<NG * PCHUNKS, 128, 0, stream>>>(zout, start, g);
}

// Round 11
// 275.818 us; speedup vs baseline: 2.3345x; 1.0319x over previous
//
#include <hip/hip_runtime.h>
#include <hip/hip_bf16.h>

#define D 128
#define NG 128

typedef __attribute__((ext_vector_type(8))) short bf16x8;
typedef __attribute__((ext_vector_type(4))) float f32x4;

__device__ inline unsigned short f2bf(float f) {
  union { float f; unsigned u; } c; c.f = f;
  unsigned u = c.u;
  return (unsigned short)((u + 0x7FFFu + ((u >> 16) & 1u)) >> 16);  // RNE
}
__device__ inline float bf2f(unsigned short b) {
  union { unsigned u; float f; } c; c.u = ((unsigned)b) << 16;
  return c.f;
}

// Transpose + bf16-convert weights: Wt[l][n][k] = bf16(W[l][k][n]).
// Also zeroes deg[]/g[] and computes pool graph bounds (folded launches).
__global__ void prep_w(const float* __restrict__ W1, const float* __restrict__ W2,
                       unsigned short* __restrict__ Wt1, unsigned short* __restrict__ Wt2,
                       int* __restrict__ deg, int N, float* __restrict__ g,
                       const int* __restrict__ batch, int* __restrict__ start) {
  int t = blockIdx.x * 256 + threadIdx.x;
  if (t < N) deg[t] = 0;
  if (t < NG * D) g[t] = 0.f;
  if (t < NG) {          // graph boundary binary search (batch is sorted)
    int lo = 0, hi = N;
    while (lo < hi) {
      int mid = (lo + hi) >> 1;
      if (batch[mid] < t) lo = mid + 1; else hi = mid;
    }
    start[t] = lo;
    if (t == 0) start[NG] = N;
  }
  if (t >= 3 * 128 * 128) return;
  int l = t >> 14, k = (t >> 7) & 127, n = t & 127;
  int o = (l << 14) + (n << 7) + k;
  Wt1[o] = f2bf(W1[t]);
  Wt2[o] = f2bf(W2[t]);
}

// ---------------- CSR build ------------------------------------------------
// Five small stream-ordered kernels. R9 measured the alternative: one
// cooperative kernel with 4 grid.sync()s ran 410us (~100us per grid-wide
// sync across 8 non-coherent XCD L2s). Stream-ordered launch boundaries ARE
// the cheap grid barrier on this chip (~3us each).

__global__ void hist_deg(const int* __restrict__ dst, int* __restrict__ deg, int E) {
  int e = blockIdx.x * 256 + threadIdx.x;
  if (e < E) atomicAdd(deg + dst[e], 1);
}

__global__ __launch_bounds__(256) void scan1(const int* __restrict__ deg,
    int* __restrict__ rowptr, int* __restrict__ bsum, int n) {
  __shared__ int sh[256];
  int tid = threadIdx.x;
  int idx = blockIdx.x * 1024 + tid * 4;
  int v[4], tsum = 0;
#pragma unroll
  for (int j = 0; j < 4; ++j) { v[j] = (idx + j < n) ? deg[idx + j] : 0; tsum += v[j]; }
  sh[tid] = tsum;
  __syncthreads();
  for (int off = 1; off < 256; off <<= 1) {
    int x = (tid >= off) ? sh[tid - off] : 0;
    __syncthreads();
    sh[tid] += x;
    __syncthreads();
  }
  if (tid == 255) bsum[blockIdx.x] = sh[255];
  int run = sh[tid] - tsum;
#pragma unroll
  for (int j = 0; j < 4; ++j) { if (idx + j < n) rowptr[idx + j] = run; run += v[j]; }
}

// single 128-thread block scan of per-block sums (nb <= 128)
__global__ __launch_bounds__(128) void scan2(int* __restrict__ bsum, int nb) {
  __shared__ int sh[128];
  int tid = threadIdx.x;
  int v = (tid < nb) ? bsum[tid] : 0;
  sh[tid] = v;
  __syncthreads();
  for (int off = 1; off < 128; off <<= 1) {
    int x = (tid >= off) ? sh[tid - off] : 0;
    __syncthreads();
    sh[tid] += x;
    __syncthreads();
  }
  if (tid < nb) bsum[tid] = sh[tid] - v;
}

__global__ void scan3(int* __restrict__ rowptr, int* __restrict__ pos,
                      const int* __restrict__ bsum, int n, int E) {
  int t = blockIdx.x * 256 + threadIdx.x;
  if (t < n) {
    int v = rowptr[t] + bsum[t >> 10];
    rowptr[t] = v;
    pos[t] = v;
  }
  if (t == 0) rowptr[n] = E;
}

__global__ void edge_scatter(const int* __restrict__ src, const int* __restrict__ dst,
                             int* __restrict__ pos, int* __restrict__ csr_src, int E) {
  int e = blockIdx.x * 256 + threadIdx.x;
  if (e >= E) return;
  int idx = atomicAdd(pos + dst[e], 1);
  csr_src[idx] = src[e];
}

// ---------------- gather aggregation: agg[i] = z[i] + sum neighbors --------
// ROOFLINED for this pattern (6 rounds of evidence): ~57us at ~3.6 TB/s
// post-L2 random-granule BW, invariant to ILP depth, lanes/node, occupancy
// and payload width (f32 512B rows = same time as bf16 256B => per-granule
// fixed cost; fp8 would gain nothing). PLAIN loads/stores: R10 measured NT
// hints as a regression (+3us, +4.4MB FETCH) -- all 8 lanes of a node read
// the same csr_src entries, which the caches serve as a broadcast; NT
// converts that into redundant post-cache traffic.

template<bool IN_BF16>
__global__ __launch_bounds__(256) void gather_agg(const void* __restrict__ zin,
    const int* __restrict__ rowptr, const int* __restrict__ csr_src,
    unsigned short* __restrict__ agg, int N) {
  int t = blockIdx.x * 256 + threadIdx.x;
  int node = t >> 3;
  if (node >= N) return;
  int c = (t & 7) * 16;    // 16 elements per lane: 32B bf16 / 64B f32
  const float* zf = (const float*)zin;
  const unsigned short* zb = (const unsigned short*)zin;

  float acc[16];

  // self term
  if constexpr (IN_BF16) {
    const unsigned short* p = zb + (size_t)node * D + c;
    bf16x8 v0 = *(const bf16x8*)(p);
    bf16x8 v1 = *(const bf16x8*)(p + 8);
#pragma unroll
    for (int j = 0; j < 8; ++j) {
      acc[j]     = bf2f((unsigned short)v0[j]);
      acc[j + 8] = bf2f((unsigned short)v1[j]);
    }
  } else {
    const float* p = zf + (size_t)node * D + c;
    float4 v0 = *(const float4*)(p);
    float4 v1 = *(const float4*)(p + 4);
    float4 v2 = *(const float4*)(p + 8);
    float4 v3 = *(const float4*)(p + 12);
    acc[0]  = v0.x; acc[1]  = v0.y; acc[2]  = v0.z; acc[3]  = v0.w;
    acc[4]  = v1.x; acc[5]  = v1.y; acc[6]  = v1.z; acc[7]  = v1.w;
    acc[8]  = v2.x; acc[9]  = v2.y; acc[10] = v2.z; acc[11] = v2.w;
    acc[12] = v3.x; acc[13] = v3.y; acc[14] = v3.z; acc[15] = v3.w;
  }

  int e  = rowptr[node];
  int e1 = rowptr[node + 1];

  if constexpr (IN_BF16) {
    for (; e + 4 <= e1; e += 4) {
      int s0 = csr_src[e + 0];
      int s1 = csr_src[e + 1];
      int s2 = csr_src[e + 2];
      int s3 = csr_src[e + 3];
      const unsigned short* p0 = zb + (size_t)s0 * D + c;
      const unsigned short* p1 = zb + (size_t)s1 * D + c;
      const unsigned short* p2 = zb + (size_t)s2 * D + c;
      const unsigned short* p3 = zb + (size_t)s3 * D + c;
      bf16x8 a0 = *(const bf16x8*)(p0), a1 = *(const bf16x8*)(p0 + 8);
      bf16x8 b0 = *(const bf16x8*)(p1), b1 = *(const bf16x8*)(p1 + 8);
      bf16x8 c0 = *(const bf16x8*)(p2), c1 = *(const bf16x8*)(p2 + 8);
      bf16x8 d0 = *(const bf16x8*)(p3), d1 = *(const bf16x8*)(p3 + 8);
#pragma unroll
      for (int j = 0; j < 8; ++j) {
        acc[j]     += (bf2f((unsigned short)a0[j]) + bf2f((unsigned short)b0[j]))
                    + (bf2f((unsigned short)c0[j]) + bf2f((unsigned short)d0[j]));
        acc[j + 8] += (bf2f((unsigned short)a1[j]) + bf2f((unsigned short)b1[j]))
                    + (bf2f((unsigned short)c1[j]) + bf2f((unsigned short)d1[j]));
      }
    }
    if (e + 2 <= e1) {
      int s0 = csr_src[e + 0];
      int s1 = csr_src[e + 1];
      const unsigned short* p0 = zb + (size_t)s0 * D + c;
      const unsigned short* p1 = zb + (size_t)s1 * D + c;
      bf16x8 a0 = *(const bf16x8*)(p0), a1 = *(const bf16x8*)(p0 + 8);
      bf16x8 b0 = *(const bf16x8*)(p1), b1 = *(const bf16x8*)(p1 + 8);
#pragma unroll
      for (int j = 0; j < 8; ++j) {
        acc[j]     += bf2f((unsigned short)a0[j]) + bf2f((unsigned short)b0[j]);
        acc[j + 8] += bf2f((unsigned short)a1[j]) + bf2f((unsigned short)b1[j]);
      }
      e += 2;
    }
    if (e < e1) {
      int s0 = csr_src[e];
      const unsigned short* p0 = zb + (size_t)s0 * D + c;
      bf16x8 a0 = *(const bf16x8*)(p0), a1 = *(const bf16x8*)(p0 + 8);
#pragma unroll
      for (int j = 0; j < 8; ++j) {
        acc[j]     += bf2f((unsigned short)a0[j]);
        acc[j + 8] += bf2f((unsigned short)a1[j]);
      }
    }
  } else {
    for (; e + 2 <= e1; e += 2) {
      int s0 = csr_src[e + 0];
      int s1 = csr_src[e + 1];
      const float* p0 = zf + (size_t)s0 * D + c;
      const float* p1 = zf + (size_t)s1 * D + c;
      float4 u0 = *(const float4*)(p0);
      float4 u1 = *(const float4*)(p0 + 4);
      float4 u2 = *(const float4*)(p0 + 8);
      float4 u3 = *(const float4*)(p0 + 12);
      float4 w0 = *(const float4*)(p1);
      float4 w1 = *(const float4*)(p1 + 4);
      float4 w2 = *(const float4*)(p1 + 8);
      float4 w3 = *(const float4*)(p1 + 12);
      acc[0]  += u0.x + w0.x; acc[1]  += u0.y + w0.y;
      acc[2]  += u0.z + w0.z; acc[3]  += u0.w + w0.w;
      acc[4]  += u1.x + w1.x; acc[5]  += u1.y + w1.y;
      acc[6]  += u1.z + w1.z; acc[7]  += u1.w + w1.w;
      acc[8]  += u2.x + w2.x; acc[9]  += u2.y + w2.y;
      acc[10] += u2.z + w2.z; acc[11] += u2.w + w2.w;
      acc[12] += u3.x + w3.x; acc[13] += u3.y + w3.y;
      acc[14] += u3.z + w3.z; acc[15] += u3.w + w3.w;
    }
    if (e < e1) {
      int s0 = csr_src[e];
      const float* p0 = zf + (size_t)s0 * D + c;
      float4 u0 = *(const float4*)(p0);
      float4 u1 = *(const float4*)(p0 + 4);
      float4 u2 = *(const float4*)(p0 + 8);
      float4 u3 = *(const float4*)(p0 + 12);
      acc[0]  += u0.x; acc[1]  += u0.y; acc[2]  += u0.z; acc[3]  += u0.w;
      acc[4]  += u1.x; acc[5]  += u1.y; acc[6]  += u1.z; acc[7]  += u1.w;
      acc[8]  += u2.x; acc[9]  += u2.y; acc[10] += u2.z; acc[11] += u2.w;
      acc[12] += u3.x; acc[13] += u3.y; acc[14] += u3.z; acc[15] += u3.w;
    }
  }

  bf16x8 o0, o1;
#pragma unroll
  for (int j = 0; j < 8; ++j) {
    o0[j] = (short)f2bf(acc[j]);
    o1[j] = (short)f2bf(acc[j + 8]);
  }
  unsigned short* q = agg + (size_t)node * D + c;
  *(bf16x8*)(q)     = o0;
  *(bf16x8*)(q + 8) = o1;
}

// ---------------- fused per-layer MLP: z = ReLU(ReLU(A@W1+b1)@W2+b2) -------
// R8 structure (near its BW floor): weights once per block (W1->reg,
// W2->LDS), 2 tiles of 128 rows, both tiles' A-fragments loaded up front,
// full 32-row warp tiles with 2-row-fragment B-reuse, warp-private hs
// (no barriers after the w2s one), staged 256B coalesced z stores.

template<bool LAST>
__global__ __launch_bounds__(256, 2) void gemm_fused(const unsigned short* __restrict__ A,
    const unsigned short* __restrict__ Wt1, const float* __restrict__ b1v,
    const unsigned short* __restrict__ Wt2, const float* __restrict__ b2v,
    unsigned short* __restrict__ Zb, float* __restrict__ Zf, int M, int nt) {
  __shared__ unsigned short w2s[128][136];
  __shared__ unsigned short hs[4][32][136];
  int tid  = threadIdx.x;
  int lane = tid & 63;
  int wid  = tid >> 6;
  int c16  = lane & 15;
  int kq   = lane >> 4;
  int koff = kq * 8;

  int tile0 = blockIdx.x * 2;
  int tile1 = tile0 + 1;

  // issue BOTH tiles' A-loads first (latency hidden under weight staging)
  bf16x8 aA[2][4], aB[2][4];
#pragma unroll
  for (int h = 0; h < 2; ++h) {
    int rowA = tile0 * 128 + wid * 32 + h * 16 + c16;
    rowA = rowA < M ? rowA : M - 1;
    int rowB = tile1 * 128 + wid * 32 + h * 16 + c16;
    rowB = rowB < M ? rowB : M - 1;
#pragma unroll
    for (int kk = 0; kk < 4; ++kk) {
      aA[h][kk] = *(const bf16x8*)(A + (size_t)rowA * D + kk * 32 + koff);
      aB[h][kk] = *(const bf16x8*)(A + (size_t)rowB * D + kk * 32 + koff);
    }
  }

  // stage W2 -> LDS (coalesced 16B chunks; 2048 chunks / 256 threads = 8 ea)
#pragma unroll
  for (int i = 0; i < 8; ++i) {
    int chunk = i * 256 + tid;
    int row = chunk >> 4, k16 = chunk & 15;
    *(bf16x8*)&w2s[row][k16 * 8] = *(const bf16x8*)(Wt2 + (size_t)row * D + k16 * 8);
  }

  // hoist W1 fragments + both biases (once per block)
  bf16x8 bf1[8][4];
  float  bb1[8], bb2[8];
#pragma unroll
  for (int fc = 0; fc < 8; ++fc) {
    int col = fc * 16 + c16;
    bb1[fc] = b1v[col];
    bb2[fc] = b2v[col];
#pragma unroll
    for (int kk = 0; kk < 4; ++kk)
      bf1[fc][kk] = *(const bf16x8*)(Wt1 + (size_t)col * D + kk * 32 + koff);
  }

  __syncthreads();   // w2s ready

  auto TILE = [&](const bf16x8 (&a)[2][4], int tile) {
    int rb = tile * 128 + wid * 32;
    // GEMM1 (full 32-row warp tile) -> hs; warp-private, in-wave ordering
#pragma unroll
    for (int fc = 0; fc < 8; ++fc) {
      f32x4 acc0 = {0.f, 0.f, 0.f, 0.f};
      f32x4 acc1 = {0.f, 0.f, 0.f, 0.f};
#pragma unroll
      for (int kk = 0; kk < 4; ++kk) {
        acc0 = __builtin_amdgcn_mfma_f32_16x16x32_bf16(a[0][kk], bf1[fc][kk], acc0, 0, 0, 0);
        acc1 = __builtin_amdgcn_mfma_f32_16x16x32_bf16(a[1][kk], bf1[fc][kk], acc1, 0, 0, 0);
      }
      int col = fc * 16 + c16;
#pragma unroll
      for (int r = 0; r < 4; ++r) {
        hs[wid][kq * 4 + r][col]      = f2bf(fmaxf(acc0[r] + bb1[fc], 0.f));
        hs[wid][kq * 4 + r + 16][col] = f2bf(fmaxf(acc1[r] + bb1[fc], 0.f));
      }
    }
    bf16x8 a2[2][4];
#pragma unroll
    for (int fr = 0; fr < 2; ++fr)
#pragma unroll
      for (int kk = 0; kk < 4; ++kk)
        a2[fr][kk] = *(const bf16x8*)&hs[wid][fr * 16 + c16][kk * 32 + koff];
    // GEMM2 (B from LDS)
#pragma unroll
    for (int fc = 0; fc < 8; ++fc) {
      f32x4 acc0 = {0.f, 0.f, 0.f, 0.f};
      f32x4 acc1 = {0.f, 0.f, 0.f, 0.f};
      int col = fc * 16 + c16;
#pragma unroll
      for (int kk = 0; kk < 4; ++kk) {
        bf16x8 b = *(const bf16x8*)&w2s[col][kk * 32 + koff];
        acc0 = __builtin_amdgcn_mfma_f32_16x16x32_bf16(a2[0][kk], b, acc0, 0, 0, 0);
        acc1 = __builtin_amdgcn_mfma_f32_16x16x32_bf16(a2[1][kk], b, acc1, 0, 0, 0);
      }
      if constexpr (LAST) {
#pragma unroll
        for (int r = 0; r < 4; ++r) {
          int row0 = rb + kq * 4 + r;
          if (row0 < M) Zf[(size_t)row0 * D + col] = fmaxf(acc0[r] + bb2[fc], 0.f);
          int row1 = row0 + 16;
          if (row1 < M) Zf[(size_t)row1 * D + col] = fmaxf(acc1[r] + bb2[fc], 0.f);
        }
      } else {
        // a2 already in registers -> safe to overwrite hs
#pragma unroll
        for (int r = 0; r < 4; ++r) {
          hs[wid][kq * 4 + r][col]      = f2bf(fmaxf(acc0[r] + bb2[fc], 0.f));
          hs[wid][kq * 4 + r + 16][col] = f2bf(fmaxf(acc1[r] + bb2[fc], 0.f));
        }
      }
    }
    if constexpr (!LAST) {
      // staged coalesced stores: per i, 4 rows x 256B contiguous segments
#pragma unroll
      for (int i = 0; i < 8; ++i) {
        int rl = i * 4 + kq;
        bf16x8 v = *(const bf16x8*)&hs[wid][rl][c16 * 8];
        int row = rb + rl;
        if (row < M)
          *(bf16x8*)(Zb + (size_t)row * D + c16 * 8) = v;
      }
    }
  };

  TILE(aA, tile0);
  if (tile1 < nt) TILE(aB, tile1);
}

// ---------------- pooling: bounds (in prep_w) + streaming mean -------------
// Each chunk atomically adds its partial sum pre-scaled by 1/len -> no
// divide pass (g zeroed in prep_w; empty graphs stay 0).

#define PCHUNKS 8
__global__ __launch_bounds__(128) void pool_mean(const float* __restrict__ z,
    const int* __restrict__ start, float* __restrict__ g) {
  int gid   = blockIdx.x >> 3;
  int chunk = blockIdx.x & (PCHUNKS - 1);
  int col = threadIdx.x;
  int s = start[gid], epos = start[gid + 1];
  int len = epos - s;
  if (len <= 0) return;
  float inv = 1.0f / (float)len;
  int per = (len + PCHUNKS - 1) / PCHUNKS;
  int r0 = s + chunk * per;
  int r1 = min(r0 + per, epos);
  if (r0 >= r1) return;
  float a0 = 0.f, a1 = 0.f, a2 = 0.f, a3 = 0.f;
  int i = r0;
  for (; i + 4 <= r1; i += 4) {
    a0 += z[(size_t)(i + 0) * D + col];
    a1 += z[(size_t)(i + 1) * D + col];
    a2 += z[(size_t)(i + 2) * D + col];
    a3 += z[(size_t)(i + 3) * D + col];
  }
  for (; i < r1; ++i) a0 += z[(size_t)i * D + col];
  atomicAdd(g + (size_t)gid * D + col, ((a0 + a1) + (a2 + a3)) * inv);
}

extern "C" void kernel_launch(void* const* d_in, const int* in_sizes, int n_in,
                              void* d_out, int out_size, void* d_ws, size_t ws_size,
                              hipStream_t stream) {
  const float* x     = (const float*)d_in[0];
  const int*   ei    = (const int*)d_in[1];
  const int*   batch = (const int*)d_in[2];
  const float* W1    = (const float*)d_in[3];
  const float* b1    = (const float*)d_in[4];
  const float* W2    = (const float*)d_in[5];
  const float* b2    = (const float*)d_in[6];

  const int N = in_sizes[0] / D;       // 100000
  const int E = in_sizes[1] / 2;       // 640000
  const int* src = ei;
  const int* dst = ei + E;

  float* zout = (float*)d_out;
  float* g    = zout + (size_t)N * D;

  // workspace layout
  char* w = (char*)d_ws;
  unsigned short* agg     = (unsigned short*)w;    w += (size_t)N * D * 2;
  unsigned short* zb      = (unsigned short*)w;    w += (size_t)N * D * 2;
  unsigned short* Wt1     = (unsigned short*)w;    w += 3 * 16384 * 2;
  unsigned short* Wt2     = (unsigned short*)w;    w += 3 * 16384 * 2;
  int*            start   = (int*)w;               w += (NG + 4) * 4;
  int*            deg     = (int*)w;               w += (size_t)N * 4;
  int*            rowptr  = (int*)w;               w += (size_t)(N + 4) * 4;
  int*            pos     = (int*)w;               w += (size_t)N * 4;
  int*            bsum    = (int*)w;               w += 128 * 4;
  int*            csr_src = (int*)w;               w += (size_t)E * 4;

  const int nb = (N + 1023) / 1024;   // 98 <= 128

  // weight prep + deg/g zero + pool bounds (folded)
  int prep_threads = (3 * 128 * 128 > N) ? 3 * 128 * 128 : N;
  prep_w<<<(prep_threads + 255) / 256, 256, 0, stream>>>(W1, W2, Wt1, Wt2, deg, N, g,
                                                         batch, start);

  // CSR build (five small stream-ordered kernels -- see comment above)
  hist_deg<<<(E + 255) / 256, 256, 0, stream>>>(dst, deg, E);
  scan1<<<nb, 256, 0, stream>>>(deg, rowptr, bsum, N);
  scan2<<<1, 128, 0, stream>>>(bsum, nb);
  scan3<<<(N + 255) / 256, 256, 0, stream>>>(rowptr, pos, bsum, N, E);
  edge_scatter<<<(E + 255) / 256, 256, 0, stream>>>(src, dst, pos, csr_src, E);

  const int gather_blocks = (int)(((size_t)N * 8 + 255) / 256);   // 3125
  const int nt            = (N + 127) / 128;                      // 782 tiles
  const int gemm_blocks   = (nt + 1) / 2;                         // 391

  // layer 0 (input f32 x)
  gather_agg<false><<<gather_blocks, 256, 0, stream>>>(x, rowptr, csr_src, agg, N);
  gemm_fused<false><<<gemm_blocks, 256, 0, stream>>>(agg, Wt1, b1, Wt2, b2, zb, zout, N, nt);
  // layer 1
  gather_agg<true><<<gather_blocks, 256, 0, stream>>>(zb, rowptr, csr_src, agg, N);
  gemm_fused<false><<<gemm_blocks, 256, 0, stream>>>(agg, Wt1 + 16384, b1 + 128,
                                                     Wt2 + 16384, b2 + 128, zb, zout, N, nt);
  // layer 2 (writes f32 zout)
  gather_agg<true><<<gather_blocks, 256, 0, stream>>>(zb, rowptr, csr_src, agg, N);
  gemm_fused<true><<<gemm_blocks, 256, 0, stream>>>(agg, Wt1 + 32768, b1 + 256,
                                                    Wt2 + 32768, b2 + 256, zb, zout, N, nt);

  pool_mean<<<NG * PCHUNKS, 128, 0, stream>>>(zout, start, g);
}